// Round 2
// baseline (190.154 us; speedup 1.0000x reference)
//
#include <hip/hip_runtime.h>
#include <hip/hip_bf16.h>
#include <stdint.h>
#include <stddef.h>

// ---- problem constants (from reference) ----
#define NNODES  100000
#define BATCH   4096
#define FDIM    128
#define MAXDEG  128
#define NEI0    25      // hop-2 samples per hop-1 node
#define NEI1    10      // hop-1 samples per seed
#define E1D     128
#define E2D     64
#define DECD    256
#define NCLS    50

// ---------------- threefry2x32 (JAX-compatible) ----------------
__host__ __device__ inline void tf2x32(uint32_t k0, uint32_t k1,
                                       uint32_t x0, uint32_t x1,
                                       uint32_t* o0, uint32_t* o1) {
  uint32_t ks[3] = {k0, k1, k0 ^ k1 ^ 0x1BD11BDAu};
  x0 += ks[0]; x1 += ks[1];
  const int rot[2][4] = {{13, 15, 26, 6}, {17, 29, 16, 24}};
  for (int i = 0; i < 5; ++i) {
    const int* r = rot[i & 1];
    for (int j = 0; j < 4; ++j) {
      x0 += x1;
      x1 = (x1 << r[j]) | (x1 >> (32 - r[j]));
      x1 ^= x0;
    }
    x0 += ks[(i + 1) % 3];
    x1 += ks[(i + 2) % 3] + (uint32_t)(i + 1);
  }
  *o0 = x0; *o1 = x1;
}

// XLA f32 ErfInv (Giles polynomial), matches lax.erf_inv for |x|<1
__device__ inline float erfinv_xla(float x) {
  float w = -log1pf(-x * x);
  float p;
  if (w < 5.0f) {
    w = w - 2.5f;
    p = 2.81022636e-08f;
    p = 3.43273939e-07f  + p * w;
    p = -3.5233877e-06f  + p * w;
    p = -4.39150654e-06f + p * w;
    p = 0.00021858087f   + p * w;
    p = -0.00125372503f  + p * w;
    p = -0.00417768164f  + p * w;
    p = 0.246640727f     + p * w;
    p = 1.50140941f      + p * w;
  } else {
    w = sqrtf(w) - 3.0f;
    p = -0.000200214257f;
    p = 0.000100950558f  + p * w;
    p = 0.00134934322f   + p * w;
    p = -0.00367342844f  + p * w;
    p = 0.00573950773f   + p * w;
    p = -0.0076224613f   + p * w;
    p = 0.00943887047f   + p * w;
    p = 1.00167406f      + p * w;
    p = 2.83297682f      + p * w;
  }
  return p * x;
}

struct PermArgs { int p1[NEI1]; int p2[NEI0]; };

// ---------------- kernels ----------------

// nb1[b*10+j] = adj[nodes[b]][p1[j]]
__global__ __launch_bounds__(256) void nb1_kernel(const int* __restrict__ nodes,
                                                  const int* __restrict__ adj,
                                                  int* __restrict__ nb1, PermArgs pa) {
  int i = blockIdx.x * blockDim.x + threadIdx.x;
  if (i >= BATCH * NEI1) return;
  int b = i / NEI1, j = i - b * NEI1;
  nb1[i] = adj[(size_t)nodes[b] * MAXDEG + pa.p1[j]];
}

// h1[i] = tanh((x1[i] + mean_j(features[nb2_ij]/deg)) @ W0), i in [0, 40960)
__global__ __launch_bounds__(128) void h1_kernel(const int* __restrict__ nb1,
                                                 const int* __restrict__ adj,
                                                 const float* __restrict__ degrees,
                                                 const float* __restrict__ features,
                                                 const float* __restrict__ W0,
                                                 float* __restrict__ h1, PermArgs pa) {
  int i = blockIdx.x;
  int f = threadIdx.x;
  __shared__ float agg[FDIM];
  __shared__ int   n2[NEI0];
  __shared__ float invd[NEI0];
  int self = nb1[i];
  if (f < NEI0) {
    int nn = adj[(size_t)self * MAXDEG + pa.p2[f]];
    n2[f] = nn;
    invd[f] = 1.0f / degrees[nn];
  }
  __syncthreads();
  float acc = 0.0f;
  for (int j = 0; j < NEI0; ++j)
    acc += features[(size_t)n2[j] * FDIM + f] * invd[j];
  agg[f] = features[(size_t)self * FDIM + f] + acc * (1.0f / NEI0);
  __syncthreads();
  float dot = 0.0f;
  for (int k = 0; k < FDIM; ++k)
    dot += agg[k] * W0[k * E1D + f];
  h1[(size_t)i * E1D + f] = tanhf(dot);
}

// h0[b] = tanh((x0[b] + mean_j(features[nb1_bj]/deg)) @ W0)
__global__ __launch_bounds__(128) void h0_kernel(const int* __restrict__ nodes,
                                                 const int* __restrict__ nb1,
                                                 const float* __restrict__ degrees,
                                                 const float* __restrict__ features,
                                                 const float* __restrict__ W0,
                                                 float* __restrict__ h0) {
  int b = blockIdx.x;
  int f = threadIdx.x;
  __shared__ float agg[FDIM];
  __shared__ int   n1[NEI1];
  __shared__ float invd[NEI1];
  if (f < NEI1) {
    int nn = nb1[b * NEI1 + f];
    n1[f] = nn;
    invd[f] = 1.0f / degrees[nn];
  }
  __syncthreads();
  float acc = 0.0f;
  for (int j = 0; j < NEI1; ++j)
    acc += features[(size_t)n1[j] * FDIM + f] * invd[j];
  agg[f] = features[(size_t)nodes[b] * FDIM + f] + acc * (1.0f / NEI1);
  __syncthreads();
  float dot = 0.0f;
  for (int k = 0; k < FDIM; ++k)
    dot += agg[k] * W0[k * E1D + f];
  h0[(size_t)b * E1D + f] = tanhf(dot);
}

// in0 = h0[b] + mean_j(h1[b*10+j]/deg1); z = in0@Wm + eps*exp(in0@Ws)
__global__ __launch_bounds__(128) void layer1_kernel(const int* __restrict__ nb1,
                                                     const float* __restrict__ degrees,
                                                     const float* __restrict__ h0,
                                                     const float* __restrict__ h1,
                                                     const float* __restrict__ Wm,
                                                     const float* __restrict__ Ws,
                                                     float* __restrict__ z,
                                                     uint32_t k3a, uint32_t k3b) {
  int b = blockIdx.x;
  int f = threadIdx.x;
  __shared__ float agg[E1D];
  __shared__ float invd[NEI1];
  if (f < NEI1) invd[f] = 1.0f / degrees[nb1[b * NEI1 + f]];
  __syncthreads();
  float acc = 0.0f;
  for (int j = 0; j < NEI1; ++j)
    acc += h1[(size_t)(b * NEI1 + j) * E1D + f] * invd[j];
  agg[f] = h0[(size_t)b * E1D + f] + acc * (1.0f / NEI1);
  __syncthreads();
  if (f < E2D) {
    float zm = 0.0f, zs = 0.0f;
    for (int k = 0; k < E1D; ++k) {
      float a = agg[k];
      zm += a * Wm[k * E2D + f];
      zs += a * Ws[k * E2D + f];
    }
    // eps bits: partitionable threefry random_bits(32) = o0 ^ o1 of cipher(key,(0,i))
    uint32_t t = (uint32_t)(b * E2D + f);
    uint32_t y0, y1;
    tf2x32(k3a, k3b, 0u, t, &y0, &y1);
    uint32_t bits = y0 ^ y1;
    uint32_t fb = (bits >> 9) | 0x3F800000u;
    float fl = __uint_as_float(fb) - 1.0f;
    const float lo = -0.99999994f;
    float u = fmaxf(lo, fl * 2.0f + lo);
    float eps = 1.4142135381698608f * erfinv_xla(u);
    z[(size_t)b * E2D + f] = zm + eps * expf(zs);
  }
}

// logits = relu(z@W1+b1)@W2 + b2; out = softmax(logits)
__global__ __launch_bounds__(256) void dec_kernel(const float* __restrict__ z,
                                                  const float* __restrict__ W1,
                                                  const float* __restrict__ b1,
                                                  const float* __restrict__ W2,
                                                  const float* __restrict__ b2,
                                                  float* __restrict__ out) {
  int b = blockIdx.x;
  int t = threadIdx.x;
  __shared__ float zr[E2D];
  __shared__ float hid[DECD];
  __shared__ float lg[NCLS];
  __shared__ float red[2];
  if (t < E2D) zr[t] = z[(size_t)b * E2D + t];
  __syncthreads();
  float h = 0.0f;
  for (int k = 0; k < E2D; ++k) h += zr[k] * W1[k * DECD + t];
  hid[t] = fmaxf(h + b1[t], 0.0f);
  __syncthreads();
  if (t < NCLS) {
    float l = 0.0f;
    for (int k = 0; k < DECD; ++k) l += hid[k] * W2[k * NCLS + t];
    lg[t] = l + b2[t];
  }
  __syncthreads();
  if (t == 0) {
    float m = -3.0e38f;
    for (int c = 0; c < NCLS; ++c) m = fmaxf(m, lg[c]);
    float s = 0.0f;
    for (int c = 0; c < NCLS; ++c) s += expf(lg[c] - m);
    red[0] = m; red[1] = s;
  }
  __syncthreads();
  if (t < NCLS) out[(size_t)b * NCLS + t] = expf(lg[t] - red[0]) / red[1];
}

// ---------------- host helpers ----------------

// jax.random.permutation(key, 128) under jax_threefry_partitionable=True:
// 1 sort round; subkey = split(key)[1] = cipher(key, 0, 1);
// sort_keys[i] = (o0 ^ o1) of cipher(subkey, 0, i); stable sort of arange(128).
static void host_permutation(uint32_t ka, uint32_t kb, int count, int* out_idx) {
  uint32_t sa, sb;
  tf2x32(ka, kb, 0u, 1u, &sa, &sb);
  uint32_t keys[MAXDEG];
  int vals[MAXDEG];
  for (int i = 0; i < MAXDEG; ++i) {
    uint32_t y0, y1;
    tf2x32(sa, sb, 0u, (uint32_t)i, &y0, &y1);
    keys[i] = y0 ^ y1;          // partitionable random_bits(32) = xor of both words
    vals[i] = i;
  }
  for (int i = 1; i < MAXDEG; ++i) {  // stable insertion sort ascending
    uint32_t kk = keys[i]; int vv = vals[i]; int j = i - 1;
    while (j >= 0 && keys[j] > kk) { keys[j+1] = keys[j]; vals[j+1] = vals[j]; --j; }
    keys[j+1] = kk; vals[j+1] = vv;
  }
  for (int i = 0; i < count; ++i) out_idx[i] = vals[i];
}

extern "C" void kernel_launch(void* const* d_in, const int* in_sizes, int n_in,
                              void* d_out, int out_size, void* d_ws, size_t ws_size,
                              hipStream_t stream) {
  const int*   nodes    = (const int*)  d_in[0];
  const int*   adj      = (const int*)  d_in[1];
  const float* degrees  = (const float*)d_in[2];
  const float* features = (const float*)d_in[3];
  const float* W0       = (const float*)d_in[4];
  const float* Wm       = (const float*)d_in[5];
  const float* Ws       = (const float*)d_in[6];
  const float* W1       = (const float*)d_in[7];
  const float* b1       = (const float*)d_in[8];
  const float* W2       = (const float*)d_in[9];
  const float* b2       = (const float*)d_in[10];
  float* out = (float*)d_out;

  // ---- reproduce reference RNG keys (jax.random.key(42), partitionable) ----
  // split(key, 3)[i] = full cipher((0,42), 0, i)
  uint32_t k1a, k1b, k2a, k2b, k3a, k3b;
  tf2x32(0u, 42u, 0u, 0u, &k1a, &k1b);
  tf2x32(0u, 42u, 0u, 1u, &k2a, &k2b);
  tf2x32(0u, 42u, 0u, 2u, &k3a, &k3b);

  PermArgs pa;
  host_permutation(k1a, k1b, NEI1, pa.p1);  // hop-1 column sample
  host_permutation(k2a, k2b, NEI0, pa.p2);  // hop-2 column sample

  // ---- workspace layout ----
  char* ws = (char*)d_ws;
  int*   nb1 = (int*)ws;                                         // 40960 ints
  float* h1  = (float*)(ws + 163840);                            // 40960*128 f32
  float* h0  = (float*)(ws + 163840 + (size_t)BATCH*NEI1*E1D*4); // 4096*128 f32
  float* z   = (float*)((char*)h0 + (size_t)BATCH*E1D*4);        // 4096*64 f32

  nb1_kernel<<<(BATCH * NEI1 + 255) / 256, 256, 0, stream>>>(nodes, adj, nb1, pa);
  h1_kernel<<<BATCH * NEI1, 128, 0, stream>>>(nb1, adj, degrees, features, W0, h1, pa);
  h0_kernel<<<BATCH, 128, 0, stream>>>(nodes, nb1, degrees, features, W0, h0);
  layer1_kernel<<<BATCH, 128, 0, stream>>>(nb1, degrees, h0, h1, Wm, Ws, z, k3a, k3b);
  dec_kernel<<<BATCH, 256, 0, stream>>>(z, W1, b1, W2, b2, out);
}

// Round 3
// 177.184 us; speedup vs baseline: 1.0732x; 1.0732x over previous
//
#include <hip/hip_runtime.h>
#include <hip/hip_bf16.h>
#include <hip/hip_fp16.h>
#include <stdint.h>
#include <stddef.h>

// ---- problem constants (from reference) ----
#define NNODES  100000
#define BATCH   4096
#define FDIM    128
#define MAXDEG  128
#define NEI0    25      // hop-2 samples per hop-1 node
#define NEI1    10      // hop-1 samples per seed
#define E1D     128
#define E2D     64
#define DECD    256
#define NCLS    50

// ---------------- threefry2x32 (JAX-compatible) ----------------
__host__ __device__ inline void tf2x32(uint32_t k0, uint32_t k1,
                                       uint32_t x0, uint32_t x1,
                                       uint32_t* o0, uint32_t* o1) {
  uint32_t ks[3] = {k0, k1, k0 ^ k1 ^ 0x1BD11BDAu};
  x0 += ks[0]; x1 += ks[1];
  const int rot[2][4] = {{13, 15, 26, 6}, {17, 29, 16, 24}};
  for (int i = 0; i < 5; ++i) {
    const int* r = rot[i & 1];
    for (int j = 0; j < 4; ++j) {
      x0 += x1;
      x1 = (x1 << r[j]) | (x1 >> (32 - r[j]));
      x1 ^= x0;
    }
    x0 += ks[(i + 1) % 3];
    x1 += ks[(i + 2) % 3] + (uint32_t)(i + 1);
  }
  *o0 = x0; *o1 = x1;
}

// XLA f32 ErfInv (Giles polynomial), matches lax.erf_inv for |x|<1
__device__ inline float erfinv_xla(float x) {
  float w = -log1pf(-x * x);
  float p;
  if (w < 5.0f) {
    w = w - 2.5f;
    p = 2.81022636e-08f;
    p = 3.43273939e-07f  + p * w;
    p = -3.5233877e-06f  + p * w;
    p = -4.39150654e-06f + p * w;
    p = 0.00021858087f   + p * w;
    p = -0.00125372503f  + p * w;
    p = -0.00417768164f  + p * w;
    p = 0.246640727f     + p * w;
    p = 1.50140941f      + p * w;
  } else {
    w = sqrtf(w) - 3.0f;
    p = -0.000200214257f;
    p = 0.000100950558f  + p * w;
    p = 0.00134934322f   + p * w;
    p = -0.00367342844f  + p * w;
    p = 0.00573950773f   + p * w;
    p = -0.0076224613f   + p * w;
    p = 0.00943887047f   + p * w;
    p = 1.00167406f      + p * w;
    p = 2.83297682f      + p * w;
  }
  return p * x;
}

struct PermArgs { int p1[NEI1]; int p2[NEI0]; };

// ---------------- kernels ----------------

// features f32 -> fp16 cache in workspace (halves gather bytes for h1)
__global__ __launch_bounds__(256) void cast_kernel(const float* __restrict__ f,
                                                   __half* __restrict__ fh) {
  int i = blockIdx.x * blockDim.x + threadIdx.x;   // one float4 per thread
  const int n4 = NNODES * FDIM / 4;
  if (i >= n4) return;
  float4 v = ((const float4*)f)[i];
  __half2 a = __floats2half2_rn(v.x, v.y);
  __half2 b = __floats2half2_rn(v.z, v.w);
  ((__half2*)fh)[2 * i]     = a;
  ((__half2*)fh)[2 * i + 1] = b;
}

// nb1[b*10+j] = adj[nodes[b]][p1[j]]
__global__ __launch_bounds__(256) void nb1_kernel(const int* __restrict__ nodes,
                                                  const int* __restrict__ adj,
                                                  int* __restrict__ nb1, PermArgs pa) {
  int i = blockIdx.x * blockDim.x + threadIdx.x;
  if (i >= BATCH * NEI1) return;
  int b = i / NEI1, j = i - b * NEI1;
  nb1[i] = adj[(size_t)nodes[b] * MAXDEG + pa.p1[j]];
}

// h1: one wave handles TWO rows; lane owns cols 2l,2l+1.
// Neighbor feature gather from fp16 cache (1 dword/lane/row); self row + W0 in f32.
__global__ __launch_bounds__(256) void h1_kernel(const int* __restrict__ nb1,
                                                 const int* __restrict__ adj,
                                                 const float* __restrict__ degrees,
                                                 const float* __restrict__ features,
                                                 const __half* __restrict__ fh,
                                                 const float* __restrict__ W0,
                                                 float* __restrict__ h1, PermArgs pa) {
  const int l = threadIdx.x & 63;
  const int w = threadIdx.x >> 6;            // wave 0..3
  const int row0 = blockIdx.x * 8 + w * 2;   // this wave's rows
  const int row1 = row0 + 1;

  __shared__ float agg[8][FDIM];             // 4 KB

  const int self0 = nb1[row0];
  const int self1 = nb1[row1];

  // lanes 0..24 hold row0's neighbor (id, 1/deg); lanes 32..56 hold row1's
  int   nnv = 0;
  float idv = 0.0f;
  if (l < NEI0) {
    int nn = adj[(size_t)self0 * MAXDEG + pa.p2[l]];
    nnv = nn; idv = 1.0f / degrees[nn];
  } else if (l >= 32 && l < 32 + NEI0) {
    int nn = adj[(size_t)self1 * MAXDEG + pa.p2[l - 32]];
    nnv = nn; idv = 1.0f / degrees[nn];
  }

  float a00 = 0.f, a01 = 0.f, a10 = 0.f, a11 = 0.f;
#pragma unroll
  for (int j = 0; j < NEI0; ++j) {
    int   nn0 = __shfl(nnv, j);        // constant lane -> v_readlane (scalar)
    float id0 = __shfl(idv, j);
    int   nn1 = __shfl(nnv, 32 + j);
    float id1 = __shfl(idv, 32 + j);
    __half2 h0v = *(const __half2*)(fh + (size_t)nn0 * FDIM + 2 * l);
    __half2 h1v = *(const __half2*)(fh + (size_t)nn1 * FDIM + 2 * l);
    float2 f0 = __half22float2(h0v);
    float2 f1 = __half22float2(h1v);
    a00 += f0.x * id0; a01 += f0.y * id0;
    a10 += f1.x * id1; a11 += f1.y * id1;
  }

  float2 s0 = ((const float2*)(features + (size_t)self0 * FDIM))[l];
  float2 s1 = ((const float2*)(features + (size_t)self1 * FDIM))[l];
  const float inv25 = 1.0f / NEI0;
  agg[w * 2][2 * l]     = s0.x + a00 * inv25;
  agg[w * 2][2 * l + 1] = s0.y + a01 * inv25;
  agg[w * 2 + 1][2 * l]     = s1.x + a10 * inv25;
  agg[w * 2 + 1][2 * l + 1] = s1.y + a11 * inv25;
  __syncthreads();

  float d00 = 0.f, d01 = 0.f, d10 = 0.f, d11 = 0.f;
#pragma unroll 4
  for (int k = 0; k < FDIM; ++k) {
    float a0 = agg[w * 2][k];          // LDS broadcast
    float a1 = agg[w * 2 + 1][k];
    float2 wv = *(const float2*)(W0 + (size_t)k * E1D + 2 * l);
    d00 += a0 * wv.x; d01 += a0 * wv.y;
    d10 += a1 * wv.x; d11 += a1 * wv.y;
  }
  ((float2*)(h1 + (size_t)row0 * E1D))[l] = make_float2(tanhf(d00), tanhf(d01));
  ((float2*)(h1 + (size_t)row1 * E1D))[l] = make_float2(tanhf(d10), tanhf(d11));
}

// h0[b] = tanh((x0[b] + mean_j(features[nb1_bj]/deg)) @ W0)
__global__ __launch_bounds__(128) void h0_kernel(const int* __restrict__ nodes,
                                                 const int* __restrict__ nb1,
                                                 const float* __restrict__ degrees,
                                                 const float* __restrict__ features,
                                                 const float* __restrict__ W0,
                                                 float* __restrict__ h0) {
  int b = blockIdx.x;
  int f = threadIdx.x;
  __shared__ float agg[FDIM];
  __shared__ int   n1[NEI1];
  __shared__ float invd[NEI1];
  if (f < NEI1) {
    int nn = nb1[b * NEI1 + f];
    n1[f] = nn;
    invd[f] = 1.0f / degrees[nn];
  }
  __syncthreads();
  float acc = 0.0f;
#pragma unroll
  for (int j = 0; j < NEI1; ++j)
    acc += features[(size_t)n1[j] * FDIM + f] * invd[j];
  agg[f] = features[(size_t)nodes[b] * FDIM + f] + acc * (1.0f / NEI1);
  __syncthreads();
  float dot = 0.0f;
  for (int k = 0; k < FDIM; ++k)
    dot += agg[k] * W0[k * E1D + f];
  h0[(size_t)b * E1D + f] = tanhf(dot);
}

// in0 = h0[b] + mean_j(h1[b*10+j]/deg1); z = in0@Wm + eps*exp(in0@Ws)
__global__ __launch_bounds__(128) void layer1_kernel(const int* __restrict__ nb1,
                                                     const float* __restrict__ degrees,
                                                     const float* __restrict__ h0,
                                                     const float* __restrict__ h1,
                                                     const float* __restrict__ Wm,
                                                     const float* __restrict__ Ws,
                                                     float* __restrict__ z,
                                                     uint32_t k3a, uint32_t k3b) {
  int b = blockIdx.x;
  int f = threadIdx.x;
  __shared__ float agg[E1D];
  __shared__ float invd[NEI1];
  if (f < NEI1) invd[f] = 1.0f / degrees[nb1[b * NEI1 + f]];
  __syncthreads();
  float acc = 0.0f;
#pragma unroll
  for (int j = 0; j < NEI1; ++j)
    acc += h1[(size_t)(b * NEI1 + j) * E1D + f] * invd[j];
  agg[f] = h0[(size_t)b * E1D + f] + acc * (1.0f / NEI1);
  __syncthreads();
  if (f < E2D) {
    float zm = 0.0f, zs = 0.0f;
    for (int k = 0; k < E1D; ++k) {
      float a = agg[k];
      zm += a * Wm[k * E2D + f];
      zs += a * Ws[k * E2D + f];
    }
    // eps bits: partitionable threefry random_bits(32) = o0 ^ o1 of cipher(key,(0,i))
    uint32_t t = (uint32_t)(b * E2D + f);
    uint32_t y0, y1;
    tf2x32(k3a, k3b, 0u, t, &y0, &y1);
    uint32_t bits = y0 ^ y1;
    uint32_t fb = (bits >> 9) | 0x3F800000u;
    float fl = __uint_as_float(fb) - 1.0f;
    const float lo = -0.99999994f;
    float u = fmaxf(lo, fl * 2.0f + lo);
    float eps = 1.4142135381698608f * erfinv_xla(u);
    z[(size_t)b * E2D + f] = zm + eps * expf(zs);
  }
}

// logits = relu(z@W1+b1)@W2 + b2; out = softmax(logits)
__global__ __launch_bounds__(256) void dec_kernel(const float* __restrict__ z,
                                                  const float* __restrict__ W1,
                                                  const float* __restrict__ b1,
                                                  const float* __restrict__ W2,
                                                  const float* __restrict__ b2,
                                                  float* __restrict__ out) {
  int b = blockIdx.x;
  int t = threadIdx.x;
  __shared__ float zr[E2D];
  __shared__ float hid[DECD];
  __shared__ float lg[NCLS];
  __shared__ float red[2];
  if (t < E2D) zr[t] = z[(size_t)b * E2D + t];
  __syncthreads();
  float h = 0.0f;
  for (int k = 0; k < E2D; ++k) h += zr[k] * W1[k * DECD + t];
  hid[t] = fmaxf(h + b1[t], 0.0f);
  __syncthreads();
  if (t < NCLS) {
    float l = 0.0f;
    for (int k = 0; k < DECD; ++k) l += hid[k] * W2[k * NCLS + t];
    lg[t] = l + b2[t];
  }
  __syncthreads();
  if (t == 0) {
    float m = -3.0e38f;
    for (int c = 0; c < NCLS; ++c) m = fmaxf(m, lg[c]);
    float s = 0.0f;
    for (int c = 0; c < NCLS; ++c) s += expf(lg[c] - m);
    red[0] = m; red[1] = s;
  }
  __syncthreads();
  if (t < NCLS) out[(size_t)b * NCLS + t] = expf(lg[t] - red[0]) / red[1];
}

// ---------------- host helpers ----------------

// jax.random.permutation(key, 128) under jax_threefry_partitionable=True:
// subkey = split(key)[1] = cipher(key, 0, 1);
// sort_keys[i] = (o0 ^ o1) of cipher(subkey, 0, i); stable sort of arange(128).
static void host_permutation(uint32_t ka, uint32_t kb, int count, int* out_idx) {
  uint32_t sa, sb;
  tf2x32(ka, kb, 0u, 1u, &sa, &sb);
  uint32_t keys[MAXDEG];
  int vals[MAXDEG];
  for (int i = 0; i < MAXDEG; ++i) {
    uint32_t y0, y1;
    tf2x32(sa, sb, 0u, (uint32_t)i, &y0, &y1);
    keys[i] = y0 ^ y1;          // partitionable random_bits(32) = xor of both words
    vals[i] = i;
  }
  for (int i = 1; i < MAXDEG; ++i) {  // stable insertion sort ascending
    uint32_t kk = keys[i]; int vv = vals[i]; int j = i - 1;
    while (j >= 0 && keys[j] > kk) { keys[j+1] = keys[j]; vals[j+1] = vals[j]; --j; }
    keys[j+1] = kk; vals[j+1] = vv;
  }
  for (int i = 0; i < count; ++i) out_idx[i] = vals[i];
}

extern "C" void kernel_launch(void* const* d_in, const int* in_sizes, int n_in,
                              void* d_out, int out_size, void* d_ws, size_t ws_size,
                              hipStream_t stream) {
  const int*   nodes    = (const int*)  d_in[0];
  const int*   adj      = (const int*)  d_in[1];
  const float* degrees  = (const float*)d_in[2];
  const float* features = (const float*)d_in[3];
  const float* W0       = (const float*)d_in[4];
  const float* Wm       = (const float*)d_in[5];
  const float* Ws       = (const float*)d_in[6];
  const float* W1       = (const float*)d_in[7];
  const float* b1       = (const float*)d_in[8];
  const float* W2       = (const float*)d_in[9];
  const float* b2       = (const float*)d_in[10];
  float* out = (float*)d_out;

  // ---- reproduce reference RNG keys (jax.random.key(42), partitionable) ----
  uint32_t k1a, k1b, k2a, k2b, k3a, k3b;
  tf2x32(0u, 42u, 0u, 0u, &k1a, &k1b);
  tf2x32(0u, 42u, 0u, 1u, &k2a, &k2b);
  tf2x32(0u, 42u, 0u, 2u, &k3a, &k3b);

  PermArgs pa;
  host_permutation(k1a, k1b, NEI1, pa.p1);  // hop-1 column sample
  host_permutation(k2a, k2b, NEI0, pa.p2);  // hop-2 column sample

  // ---- workspace layout ----
  char* ws = (char*)d_ws;
  int*    nb1 = (int*)ws;                                        // 40960 ints (163840 B)
  float*  h1  = (float*)(ws + 163840);                           // 40960*128 f32 (20971520 B)
  float*  h0  = (float*)(ws + 163840 + 20971520);                // 4096*128 f32 (2097152 B)
  float*  z   = (float*)(ws + 163840 + 20971520 + 2097152);      // 4096*64 f32 (1048576 B)
  __half* fh  = (__half*)(ws + 163840 + 20971520 + 2097152 + 1048576); // 100000*128 fp16 (25.6 MB)

  cast_kernel<<<(NNODES * FDIM / 4 + 255) / 256, 256, 0, stream>>>(features, fh);
  nb1_kernel<<<(BATCH * NEI1 + 255) / 256, 256, 0, stream>>>(nodes, adj, nb1, pa);
  h1_kernel<<<BATCH * NEI1 / 8, 256, 0, stream>>>(nb1, adj, degrees, features, fh, W0, h1, pa);
  h0_kernel<<<BATCH, 128, 0, stream>>>(nodes, nb1, degrees, features, W0, h0);
  layer1_kernel<<<BATCH, 128, 0, stream>>>(nb1, degrees, h0, h1, Wm, Ws, z, k3a, k3b);
  dec_kernel<<<BATCH, 256, 0, stream>>>(z, W1, b1, W2, b2, out);
}

// Round 4
// 121.194 us; speedup vs baseline: 1.5690x; 1.4620x over previous
//
#include <hip/hip_runtime.h>
#include <hip/hip_bf16.h>
#include <hip/hip_fp16.h>
#include <stdint.h>
#include <stddef.h>

// ---- problem constants (from reference) ----
#define NNODES  100000
#define BATCH   4096
#define FDIM    128
#define MAXDEG  128
#define NEI0    25      // hop-2 samples per hop-1 node
#define NEI1    10      // hop-1 samples per seed
#define E1D     128
#define E2D     64
#define DECD    256
#define NCLS    50

// ---------------- threefry2x32 (JAX-compatible) ----------------
__host__ __device__ inline void tf2x32(uint32_t k0, uint32_t k1,
                                       uint32_t x0, uint32_t x1,
                                       uint32_t* o0, uint32_t* o1) {
  uint32_t ks[3] = {k0, k1, k0 ^ k1 ^ 0x1BD11BDAu};
  x0 += ks[0]; x1 += ks[1];
  const int rot[2][4] = {{13, 15, 26, 6}, {17, 29, 16, 24}};
  for (int i = 0; i < 5; ++i) {
    const int* r = rot[i & 1];
    for (int j = 0; j < 4; ++j) {
      x0 += x1;
      x1 = (x1 << r[j]) | (x1 >> (32 - r[j]));
      x1 ^= x0;
    }
    x0 += ks[(i + 1) % 3];
    x1 += ks[(i + 2) % 3] + (uint32_t)(i + 1);
  }
  *o0 = x0; *o1 = x1;
}

// XLA f32 ErfInv (Giles polynomial), matches lax.erf_inv for |x|<1
__device__ inline float erfinv_xla(float x) {
  float w = -log1pf(-x * x);
  float p;
  if (w < 5.0f) {
    w = w - 2.5f;
    p = 2.81022636e-08f;
    p = 3.43273939e-07f  + p * w;
    p = -3.5233877e-06f  + p * w;
    p = -4.39150654e-06f + p * w;
    p = 0.00021858087f   + p * w;
    p = -0.00125372503f  + p * w;
    p = -0.00417768164f  + p * w;
    p = 0.246640727f     + p * w;
    p = 1.50140941f      + p * w;
  } else {
    w = sqrtf(w) - 3.0f;
    p = -0.000200214257f;
    p = 0.000100950558f  + p * w;
    p = 0.00134934322f   + p * w;
    p = -0.00367342844f  + p * w;
    p = 0.00573950773f   + p * w;
    p = -0.0076224613f   + p * w;
    p = 0.00943887047f   + p * w;
    p = 1.00167406f      + p * w;
    p = 2.83297682f      + p * w;
  }
  return p * x;
}

struct PermArgs { int p1[NEI1]; int p2[NEI0]; };

#define CAST_FBLKS 12500   // 100000*128/4/256
#define CAST_WBLKS 16      // 128*128/4/256
#define NB1_BLKS   160     // 40960/256

// prep: features f32->fp16, W0 f32->fp16, nb1 gather — one fused launch
__global__ __launch_bounds__(256) void prep_kernel(const float* __restrict__ f,
                                                   __half* __restrict__ fh,
                                                   const float* __restrict__ W0,
                                                   __half* __restrict__ W0h,
                                                   const int* __restrict__ nodes,
                                                   const int* __restrict__ adj,
                                                   int* __restrict__ nb1, PermArgs pa) {
  int bx = blockIdx.x;
  if (bx < CAST_FBLKS) {
    int i = bx * 256 + threadIdx.x;
    float4 v = ((const float4*)f)[i];
    ((__half2*)fh)[2 * i]     = __floats2half2_rn(v.x, v.y);
    ((__half2*)fh)[2 * i + 1] = __floats2half2_rn(v.z, v.w);
  } else if (bx < CAST_FBLKS + CAST_WBLKS) {
    int i = (bx - CAST_FBLKS) * 256 + threadIdx.x;
    float4 v = ((const float4*)W0)[i];
    ((__half2*)W0h)[2 * i]     = __floats2half2_rn(v.x, v.y);
    ((__half2*)W0h)[2 * i + 1] = __floats2half2_rn(v.z, v.w);
  } else {
    int i = (bx - CAST_FBLKS - CAST_WBLKS) * 256 + threadIdx.x;
    int b = i / NEI1, j = i - b * NEI1;
    nb1[i] = adj[(size_t)nodes[b] * MAXDEG + pa.p1[j]];
  }
}

#define H1_ROWS 16   // rows per block (4 waves x 4 rows)

// h1[i] = tanh((x1[i] + mean_j(fh[nb2_ij]/deg)) @ W0), i in [0, 40960)
// Wave handles 4 rows; lane owns 8 fp16 cols of row (l>>4); 25 independent
// dwordx4 gathers into a register array -> MLP=25 per wave.
__global__ __launch_bounds__(256, 2) void h1_kernel(const int* __restrict__ nb1,
                                                    const int* __restrict__ adj,
                                                    const float* __restrict__ degrees,
                                                    const __half* __restrict__ fh,
                                                    const __half* __restrict__ W0h,
                                                    float* __restrict__ h1, PermArgs pa) {
  const int t = threadIdx.x;
  const int row_base = blockIdx.x * H1_ROWS;
  __shared__ int   self_lds[H1_ROWS];
  __shared__ int   nn_lds[H1_ROWS][NEI0];
  __shared__ float id_lds[H1_ROWS][NEI0];
  __shared__ float agg[H1_ROWS][FDIM];

  if (t < H1_ROWS) self_lds[t] = nb1[row_base + t];
  __syncthreads();
  for (int i = t; i < H1_ROWS * NEI0; i += 256) {
    int r = i / NEI0, j = i - r * NEI0;
    int nn = adj[(size_t)self_lds[r] * MAXDEG + pa.p2[j]];
    nn_lds[r][j] = nn;
    id_lds[r][j] = 1.0f / degrees[nn];
  }
  __syncthreads();

  const int l = t & 63, w = t >> 6;
  const int r  = w * 4 + (l >> 4);          // gather-phase row
  const int c0 = (l & 15) * 8;              // 8 fp16 columns

  uint4 vv[NEI0];
#pragma unroll
  for (int j = 0; j < NEI0; ++j)
    vv[j] = *(const uint4*)(fh + (size_t)nn_lds[r][j] * FDIM + c0);
  uint4 sv = *(const uint4*)(fh + (size_t)self_lds[r] * FDIM + c0);

  float acc[8] = {0, 0, 0, 0, 0, 0, 0, 0};
#pragma unroll
  for (int j = 0; j < NEI0; ++j) {
    float id = id_lds[r][j];
    const __half2* hp = (const __half2*)&vv[j];
#pragma unroll
    for (int q = 0; q < 4; ++q) {
      float2 f2 = __half22float2(hp[q]);
      acc[2 * q]     += f2.x * id;
      acc[2 * q + 1] += f2.y * id;
    }
  }
  {
    const __half2* sp = (const __half2*)&sv;
    const float inv25 = 1.0f / NEI0;
#pragma unroll
    for (int q = 0; q < 4; ++q) {
      float2 f2 = __half22float2(sp[q]);
      agg[r][c0 + 2 * q]     = f2.x + acc[2 * q] * inv25;
      agg[r][c0 + 2 * q + 1] = f2.y + acc[2 * q + 1] * inv25;
    }
  }
  __syncthreads();

  // GEMM: wave w -> rows 4w..4w+3; lane cols {2l, 2l+1}
  float d[4][2] = {{0,0},{0,0},{0,0},{0,0}};
  const int w4 = w * 4;
#pragma unroll 4
  for (int k4 = 0; k4 < FDIM; k4 += 4) {
    float4 a0 = *(const float4*)&agg[w4 + 0][k4];
    float4 a1 = *(const float4*)&agg[w4 + 1][k4];
    float4 a2 = *(const float4*)&agg[w4 + 2][k4];
    float4 a3 = *(const float4*)&agg[w4 + 3][k4];
    float a0v[4] = {a0.x, a0.y, a0.z, a0.w};
    float a1v[4] = {a1.x, a1.y, a1.z, a1.w};
    float a2v[4] = {a2.x, a2.y, a2.z, a2.w};
    float a3v[4] = {a3.x, a3.y, a3.z, a3.w};
#pragma unroll
    for (int kk = 0; kk < 4; ++kk) {
      float2 wv = __half22float2(*(const __half2*)(W0h + (size_t)(k4 + kk) * E1D + 2 * l));
      d[0][0] += a0v[kk] * wv.x; d[0][1] += a0v[kk] * wv.y;
      d[1][0] += a1v[kk] * wv.x; d[1][1] += a1v[kk] * wv.y;
      d[2][0] += a2v[kk] * wv.x; d[2][1] += a2v[kk] * wv.y;
      d[3][0] += a3v[kk] * wv.x; d[3][1] += a3v[kk] * wv.y;
    }
  }
#pragma unroll
  for (int rr = 0; rr < 4; ++rr) {
    int row = row_base + w4 + rr;
    ((float2*)(h1 + (size_t)row * E1D))[l] =
        make_float2(tanhf(d[rr][0]), tanhf(d[rr][1]));
  }
}

// h0: 4 seeds per block; neighbors+self f32; W0 fp16
__global__ __launch_bounds__(256) void h0_kernel(const int* __restrict__ nodes,
                                                 const int* __restrict__ nb1,
                                                 const float* __restrict__ degrees,
                                                 const float* __restrict__ features,
                                                 const __half* __restrict__ W0h,
                                                 float* __restrict__ h0) {
  const int t = threadIdx.x;
  const int s_base = blockIdx.x * 4;
  __shared__ float agg[4][FDIM];
  __shared__ int   nn_lds[4][NEI1];
  __shared__ float id_lds[4][NEI1];
  if (t < 4 * NEI1) {
    int r = t / NEI1, j = t - r * NEI1;
    int nn = nb1[(s_base + r) * NEI1 + j];
    nn_lds[r][j] = nn;
    id_lds[r][j] = 1.0f / degrees[nn];
  }
  __syncthreads();
  {
    int f = t & 127, rr = t >> 7;
#pragma unroll
    for (int h = 0; h < 2; ++h) {
      int r = rr + 2 * h;
      float acc = 0.0f;
#pragma unroll
      for (int j = 0; j < NEI1; ++j)
        acc += features[(size_t)nn_lds[r][j] * FDIM + f] * id_lds[r][j];
      agg[r][f] = features[(size_t)nodes[s_base + r] * FDIM + f] + acc * (1.0f / NEI1);
    }
  }
  __syncthreads();
  const int p = t & 63, q = t >> 6;    // row q, cols {2p, 2p+1}
  float d0 = 0.f, d1 = 0.f;
#pragma unroll 4
  for (int k4 = 0; k4 < FDIM; k4 += 4) {
    float4 a = *(const float4*)&agg[q][k4];
    float av[4] = {a.x, a.y, a.z, a.w};
#pragma unroll
    for (int kk = 0; kk < 4; ++kk) {
      float2 wv = __half22float2(*(const __half2*)(W0h + (size_t)(k4 + kk) * E1D + 2 * p));
      d0 += av[kk] * wv.x; d1 += av[kk] * wv.y;
    }
  }
  ((float2*)(h0 + (size_t)(s_base + q) * E1D))[p] = make_float2(tanhf(d0), tanhf(d1));
}

// layer1: 4 seeds per block; z = agg@Wm + eps*exp(agg@Ws)
__global__ __launch_bounds__(256) void layer1_kernel(const int* __restrict__ nb1,
                                                     const float* __restrict__ degrees,
                                                     const float* __restrict__ h0,
                                                     const float* __restrict__ h1,
                                                     const float* __restrict__ Wm,
                                                     const float* __restrict__ Ws,
                                                     float* __restrict__ z,
                                                     uint32_t k3a, uint32_t k3b) {
  const int t = threadIdx.x;
  const int s_base = blockIdx.x * 4;
  __shared__ float agg[4][E1D];
  __shared__ float id_lds[4][NEI1];
  if (t < 4 * NEI1) {
    int r = t / NEI1, j = t - r * NEI1;
    id_lds[r][j] = 1.0f / degrees[nb1[(s_base + r) * NEI1 + j]];
  }
  __syncthreads();
  {
    int f = t & 127, rr = t >> 7;
#pragma unroll
    for (int h = 0; h < 2; ++h) {
      int r = rr + 2 * h;
      float acc = 0.0f;
#pragma unroll
      for (int j = 0; j < NEI1; ++j)
        acc += h1[(size_t)((s_base + r) * NEI1 + j) * E1D + f] * id_lds[r][j];
      agg[r][f] = h0[(size_t)(s_base + r) * E1D + f] + acc * (1.0f / NEI1);
    }
  }
  __syncthreads();
  const int c = t & 63, q = t >> 6;    // row q, col c
  float zm = 0.f, zs = 0.f;
#pragma unroll 4
  for (int k4 = 0; k4 < E1D; k4 += 4) {
    float4 a = *(const float4*)&agg[q][k4];
    float av[4] = {a.x, a.y, a.z, a.w};
#pragma unroll
    for (int kk = 0; kk < 4; ++kk) {
      zm += av[kk] * Wm[(size_t)(k4 + kk) * E2D + c];
      zs += av[kk] * Ws[(size_t)(k4 + kk) * E2D + c];
    }
  }
  int b = s_base + q;
  uint32_t tt = (uint32_t)(b * E2D + c);
  uint32_t y0, y1;
  tf2x32(k3a, k3b, 0u, tt, &y0, &y1);
  uint32_t bits = y0 ^ y1;
  uint32_t fb = (bits >> 9) | 0x3F800000u;
  float fl = __uint_as_float(fb) - 1.0f;
  const float lo = -0.99999994f;
  float u = fmaxf(lo, fl * 2.0f + lo);
  float eps = 1.4142135381698608f * erfinv_xla(u);
  z[(size_t)b * E2D + c] = zm + eps * expf(zs);
}

// dec: 4 rows per block; logits = relu(z@W1+b1)@W2+b2; softmax
__global__ __launch_bounds__(256) void dec_kernel(const float* __restrict__ z,
                                                  const float* __restrict__ W1,
                                                  const float* __restrict__ b1,
                                                  const float* __restrict__ W2,
                                                  const float* __restrict__ b2,
                                                  float* __restrict__ out) {
  const int t = threadIdx.x;
  const int s_base = blockIdx.x * 4;
  __shared__ float zr[4][E2D];
  __shared__ float hid[4][DECD];
  __shared__ float lg[4][NCLS];
  zr[t >> 6][t & 63] = z[(size_t)s_base * E2D + t];
  __syncthreads();
  float h[4] = {0, 0, 0, 0};
#pragma unroll 4
  for (int k = 0; k < E2D; ++k) {
    float wv = W1[(size_t)k * DECD + t];
#pragma unroll
    for (int r = 0; r < 4; ++r) h[r] += zr[r][k] * wv;
  }
  float bb = b1[t];
#pragma unroll
  for (int r = 0; r < 4; ++r) hid[r][t] = fmaxf(h[r] + bb, 0.0f);
  __syncthreads();
  if (t < 4 * NCLS) {
    int r = t / NCLS, c = t - r * NCLS;
    float acc = 0.0f;
#pragma unroll 4
    for (int k = 0; k < DECD; ++k) acc += hid[r][k] * W2[(size_t)k * NCLS + c];
    lg[r][c] = acc + b2[c];
  }
  __syncthreads();
  const int l = t & 63, w = t >> 6;   // wave w -> row w
  float v = (l < NCLS) ? lg[w][l] : -3.0e38f;
  float m = v;
#pragma unroll
  for (int off = 32; off; off >>= 1) m = fmaxf(m, __shfl_xor(m, off));
  float e = (l < NCLS) ? expf(v - m) : 0.0f;
  float s = e;
#pragma unroll
  for (int off = 32; off; off >>= 1) s += __shfl_xor(s, off);
  if (l < NCLS) out[(size_t)(s_base + w) * NCLS + l] = e / s;
}

// ---------------- host helpers ----------------

// jax.random.permutation(key, 128), jax_threefry_partitionable:
// subkey = split(key)[1] = cipher(key, 0, 1);
// sort_keys[i] = (o0 ^ o1) of cipher(subkey, 0, i); stable sort of arange(128).
static void host_permutation(uint32_t ka, uint32_t kb, int count, int* out_idx) {
  uint32_t sa, sb;
  tf2x32(ka, kb, 0u, 1u, &sa, &sb);
  uint32_t keys[MAXDEG];
  int vals[MAXDEG];
  for (int i = 0; i < MAXDEG; ++i) {
    uint32_t y0, y1;
    tf2x32(sa, sb, 0u, (uint32_t)i, &y0, &y1);
    keys[i] = y0 ^ y1;
    vals[i] = i;
  }
  for (int i = 1; i < MAXDEG; ++i) {
    uint32_t kk = keys[i]; int vv = vals[i]; int j = i - 1;
    while (j >= 0 && keys[j] > kk) { keys[j+1] = keys[j]; vals[j+1] = vals[j]; --j; }
    keys[j+1] = kk; vals[j+1] = vv;
  }
  for (int i = 0; i < count; ++i) out_idx[i] = vals[i];
}

extern "C" void kernel_launch(void* const* d_in, const int* in_sizes, int n_in,
                              void* d_out, int out_size, void* d_ws, size_t ws_size,
                              hipStream_t stream) {
  const int*   nodes    = (const int*)  d_in[0];
  const int*   adj      = (const int*)  d_in[1];
  const float* degrees  = (const float*)d_in[2];
  const float* features = (const float*)d_in[3];
  const float* W0       = (const float*)d_in[4];
  const float* Wm       = (const float*)d_in[5];
  const float* Ws       = (const float*)d_in[6];
  const float* W1       = (const float*)d_in[7];
  const float* b1       = (const float*)d_in[8];
  const float* W2       = (const float*)d_in[9];
  const float* b2       = (const float*)d_in[10];
  float* out = (float*)d_out;

  uint32_t k1a, k1b, k2a, k2b, k3a, k3b;
  tf2x32(0u, 42u, 0u, 0u, &k1a, &k1b);
  tf2x32(0u, 42u, 0u, 1u, &k2a, &k2b);
  tf2x32(0u, 42u, 0u, 2u, &k3a, &k3b);

  PermArgs pa;
  host_permutation(k1a, k1b, NEI1, pa.p1);
  host_permutation(k2a, k2b, NEI0, pa.p2);

  // ---- workspace layout ----
  char* ws = (char*)d_ws;
  int*    nb1 = (int*)ws;                                   // 163840 B
  float*  h1  = (float*)(ws + 163840);                      // 20971520 B
  float*  h0  = (float*)(ws + 163840 + 20971520);           // 2097152 B
  float*  z   = (float*)(ws + 163840 + 20971520 + 2097152); // 1048576 B
  __half* fh  = (__half*)(ws + 163840 + 20971520 + 2097152 + 1048576);   // 25600000 B
  __half* W0h = (__half*)(ws + 163840 + 20971520 + 2097152 + 1048576 + 25600000); // 32768 B

  prep_kernel<<<CAST_FBLKS + CAST_WBLKS + NB1_BLKS, 256, 0, stream>>>(
      features, fh, W0, W0h, nodes, adj, nb1, pa);
  h1_kernel<<<BATCH * NEI1 / H1_ROWS, 256, 0, stream>>>(
      nb1, adj, degrees, fh, W0h, h1, pa);
  h0_kernel<<<BATCH / 4, 256, 0, stream>>>(nodes, nb1, degrees, features, W0h, h0);
  layer1_kernel<<<BATCH / 4, 256, 0, stream>>>(nb1, degrees, h0, h1, Wm, Ws, z, k3a, k3b);
  dec_kernel<<<BATCH / 4, 256, 0, stream>>>(z, W1, b1, W2, b2, out);
}

// Round 5
// 111.265 us; speedup vs baseline: 1.7090x; 1.0892x over previous
//
#include <hip/hip_runtime.h>
#include <hip/hip_bf16.h>
#include <hip/hip_fp16.h>
#include <stdint.h>
#include <stddef.h>

// ---- problem constants (from reference) ----
#define NNODES  100000
#define BATCH   4096
#define FDIM    128
#define MAXDEG  128
#define NEI0    25      // hop-2 samples per hop-1 node
#define NEI1    10      // hop-1 samples per seed
#define E1D     128
#define E2D     64
#define DECD    256
#define NCLS    50

typedef _Float16 half8 __attribute__((ext_vector_type(8)));
typedef float f32x4 __attribute__((ext_vector_type(4)));

// ---------------- threefry2x32 (JAX-compatible) ----------------
__host__ __device__ inline void tf2x32(uint32_t k0, uint32_t k1,
                                       uint32_t x0, uint32_t x1,
                                       uint32_t* o0, uint32_t* o1) {
  uint32_t ks[3] = {k0, k1, k0 ^ k1 ^ 0x1BD11BDAu};
  x0 += ks[0]; x1 += ks[1];
  const int rot[2][4] = {{13, 15, 26, 6}, {17, 29, 16, 24}};
  for (int i = 0; i < 5; ++i) {
    const int* r = rot[i & 1];
    for (int j = 0; j < 4; ++j) {
      x0 += x1;
      x1 = (x1 << r[j]) | (x1 >> (32 - r[j]));
      x1 ^= x0;
    }
    x0 += ks[(i + 1) % 3];
    x1 += ks[(i + 2) % 3] + (uint32_t)(i + 1);
  }
  *o0 = x0; *o1 = x1;
}

// XLA f32 ErfInv (Giles polynomial), matches lax.erf_inv for |x|<1
__device__ inline float erfinv_xla(float x) {
  float w = -log1pf(-x * x);
  float p;
  if (w < 5.0f) {
    w = w - 2.5f;
    p = 2.81022636e-08f;
    p = 3.43273939e-07f  + p * w;
    p = -3.5233877e-06f  + p * w;
    p = -4.39150654e-06f + p * w;
    p = 0.00021858087f   + p * w;
    p = -0.00125372503f  + p * w;
    p = -0.00417768164f  + p * w;
    p = 0.246640727f     + p * w;
    p = 1.50140941f      + p * w;
  } else {
    w = sqrtf(w) - 3.0f;
    p = -0.000200214257f;
    p = 0.000100950558f  + p * w;
    p = 0.00134934322f   + p * w;
    p = -0.00367342844f  + p * w;
    p = 0.00573950773f   + p * w;
    p = -0.0076224613f   + p * w;
    p = 0.00943887047f   + p * w;
    p = 1.00167406f      + p * w;
    p = 2.83297682f      + p * w;
  }
  return p * x;
}

struct PermArgs { int p1[NEI1]; int p2[NEI0]; };

#define CAST_FBLKS 12500   // 100000*128/4/256
#define CAST_WBLKS 16      // 128*128/4/256
#define WT_BLKS    8       // 128*128/8/256 (transposed cast)
#define NB1_BLKS   160     // 40960/256

// prep: features f32->fp16, W0 f32->fp16 (+transposed), nb1 gather
__global__ __launch_bounds__(256) void prep_kernel(const float* __restrict__ f,
                                                   __half* __restrict__ fh,
                                                   const float* __restrict__ W0,
                                                   __half* __restrict__ W0h,
                                                   __half* __restrict__ W0ht,
                                                   const int* __restrict__ nodes,
                                                   const int* __restrict__ adj,
                                                   int* __restrict__ nb1, PermArgs pa) {
  int bx = blockIdx.x;
  if (bx < CAST_FBLKS) {
    int i = bx * 256 + threadIdx.x;
    float4 v = ((const float4*)f)[i];
    ((__half2*)fh)[2 * i]     = __floats2half2_rn(v.x, v.y);
    ((__half2*)fh)[2 * i + 1] = __floats2half2_rn(v.z, v.w);
  } else if (bx < CAST_FBLKS + CAST_WBLKS) {
    int i = (bx - CAST_FBLKS) * 256 + threadIdx.x;
    float4 v = ((const float4*)W0)[i];
    ((__half2*)W0h)[2 * i]     = __floats2half2_rn(v.x, v.y);
    ((__half2*)W0h)[2 * i + 1] = __floats2half2_rn(v.z, v.w);
  } else if (bx < CAST_FBLKS + CAST_WBLKS + WT_BLKS) {
    // W0ht[n][k] = (half)W0[k][n]
    int i = (bx - CAST_FBLKS - CAST_WBLKS) * 256 + threadIdx.x; // 0..2047
    int n  = i >> 4;
    int kb = (i & 15) * 8;
    uint4 ov;
    uint32_t* op = (uint32_t*)&ov;
#pragma unroll
    for (int q = 0; q < 4; ++q) {
      float a = W0[(size_t)(kb + 2 * q)     * E1D + n];
      float b = W0[(size_t)(kb + 2 * q + 1) * E1D + n];
      __half2 h = __floats2half2_rn(a, b);
      op[q] = __builtin_bit_cast(uint32_t, h);
    }
    *(uint4*)(W0ht + (size_t)n * FDIM + kb) = ov;
  } else {
    int i = (bx - CAST_FBLKS - CAST_WBLKS - WT_BLKS) * 256 + threadIdx.x;
    int b = i / NEI1, j = i - b * NEI1;
    nb1[i] = adj[(size_t)nodes[b] * MAXDEG + pa.p1[j]];
  }
}

#define H1_ROWS 16   // rows per block (4 waves x 4 rows gather; GEMM all-rows/wave)

// h1[i] = tanh((x1[i] + mean_j(fh[nb2_ij]/deg)) @ W0)
// Gather: software-pipelined batches (8/8/9) of named uint4 regs -> deep MLP.
// GEMM: fp16 agg in swizzled LDS + mfma_f32_16x16x32_f16 against W0ht.
__global__ __launch_bounds__(256, 2) void h1_kernel(const int* __restrict__ nb1,
                                                    const int* __restrict__ adj,
                                                    const float* __restrict__ degrees,
                                                    const __half* __restrict__ fh,
                                                    const __half* __restrict__ W0ht,
                                                    float* __restrict__ h1, PermArgs pa) {
  const int t = threadIdx.x;
  const int row_base = blockIdx.x * H1_ROWS;
  __shared__ int    self_lds[H1_ROWS];
  __shared__ int    nn_lds[H1_ROWS][NEI0];
  __shared__ float  id_lds[H1_ROWS][NEI0];
  __shared__ __half agg_h[H1_ROWS][FDIM];    // XOR-swizzled rows, 4 KB

  if (t < H1_ROWS) self_lds[t] = nb1[row_base + t];
  __syncthreads();
  for (int i = t; i < H1_ROWS * NEI0; i += 256) {
    int r = i / NEI0, j = i - r * NEI0;
    int nn = adj[(size_t)self_lds[r] * MAXDEG + pa.p2[j]];
    nn_lds[r][j] = nn;
    id_lds[r][j] = 1.0f / degrees[nn];
  }
  __syncthreads();

  const int l = t & 63, w = t >> 6;
  const int r  = w * 4 + (l >> 4);          // gather-phase row
  const int c0 = (l & 15) * 8;              // 8 fp16 columns owned
  const __half* frc = fh + c0;
  const int*   nn_r = nn_lds[r];
  const float* id_r = id_lds[r];

  float acc0 = 0, acc1 = 0, acc2 = 0, acc3 = 0, acc4 = 0, acc5 = 0, acc6 = 0, acc7 = 0;

#define LDN(var, j) var = *(const uint4*)(frc + (size_t)nn_r[(j)] * FDIM)
#define CONS(vv, idv) do { \
    const __half2* hp_ = (const __half2*)&(vv); \
    float id_ = (idv); \
    float2 f0_ = __half22float2(hp_[0]); \
    float2 f1_ = __half22float2(hp_[1]); \
    float2 f2_ = __half22float2(hp_[2]); \
    float2 f3_ = __half22float2(hp_[3]); \
    acc0 += f0_.x * id_; acc1 += f0_.y * id_; \
    acc2 += f1_.x * id_; acc3 += f1_.y * id_; \
    acc4 += f2_.x * id_; acc5 += f2_.y * id_; \
    acc6 += f3_.x * id_; acc7 += f3_.y * id_; \
  } while (0)

  uint4 v0, v1, v2, v3, v4, v5, v6, v7;
  uint4 u0, u1, u2, u3, u4, u5, u6, u7;
  uint4 x24, sv;
  // batch A issue
  LDN(v0, 0); LDN(v1, 1); LDN(v2, 2); LDN(v3, 3);
  LDN(v4, 4); LDN(v5, 5); LDN(v6, 6); LDN(v7, 7);
  // batch B issue
  LDN(u0, 8); LDN(u1, 9); LDN(u2, 10); LDN(u3, 11);
  LDN(u4, 12); LDN(u5, 13); LDN(u6, 14); LDN(u7, 15);
  // consume A
  CONS(v0, id_r[0]); CONS(v1, id_r[1]); CONS(v2, id_r[2]); CONS(v3, id_r[3]);
  CONS(v4, id_r[4]); CONS(v5, id_r[5]); CONS(v6, id_r[6]); CONS(v7, id_r[7]);
  // batch C issue (reuse A regs) + self
  LDN(v0, 16); LDN(v1, 17); LDN(v2, 18); LDN(v3, 19);
  LDN(v4, 20); LDN(v5, 21); LDN(v6, 22); LDN(v7, 23);
  LDN(x24, 24);
  sv = *(const uint4*)(frc + (size_t)self_lds[r] * FDIM);
  // consume B
  CONS(u0, id_r[8]);  CONS(u1, id_r[9]);  CONS(u2, id_r[10]); CONS(u3, id_r[11]);
  CONS(u4, id_r[12]); CONS(u5, id_r[13]); CONS(u6, id_r[14]); CONS(u7, id_r[15]);
  // consume C
  CONS(v0, id_r[16]); CONS(v1, id_r[17]); CONS(v2, id_r[18]); CONS(v3, id_r[19]);
  CONS(v4, id_r[20]); CONS(v5, id_r[21]); CONS(v6, id_r[22]); CONS(v7, id_r[23]);
  CONS(x24, id_r[24]);
#undef LDN
#undef CONS

  // agg = self + acc/25, stored fp16 to swizzled LDS
  {
    const float inv25 = 1.0f / NEI0;
    const __half2* sp = (const __half2*)&sv;
    float2 s0 = __half22float2(sp[0]);
    float2 s1 = __half22float2(sp[1]);
    float2 s2 = __half22float2(sp[2]);
    float2 s3 = __half22float2(sp[3]);
    uint4 ov;
    uint32_t* op = (uint32_t*)&ov;
    __half2 o0 = __floats2half2_rn(s0.x + acc0 * inv25, s0.y + acc1 * inv25);
    __half2 o1 = __floats2half2_rn(s1.x + acc2 * inv25, s1.y + acc3 * inv25);
    __half2 o2 = __floats2half2_rn(s2.x + acc4 * inv25, s2.y + acc5 * inv25);
    __half2 o3 = __floats2half2_rn(s3.x + acc6 * inv25, s3.y + acc7 * inv25);
    op[0] = __builtin_bit_cast(uint32_t, o0);
    op[1] = __builtin_bit_cast(uint32_t, o1);
    op[2] = __builtin_bit_cast(uint32_t, o2);
    op[3] = __builtin_bit_cast(uint32_t, o3);
    char* wb = (char*)agg_h + r * 256 + ((c0 * 2) ^ ((r & 7) << 4));
    *(uint4*)wb = ov;
  }
  __syncthreads();

  // MFMA GEMM: wave w -> cols [32w, 32w+32); all 16 rows.
  // A: lane row lr=l&15, k-quarter kq=l>>4; B from W0ht (contiguous k).
  {
    const int lr = l & 15, kq = l >> 4;
    const __half* wt0 = W0ht + (size_t)(w * 32 + lr) * FDIM + kq * 8;
    const __half* wt1 = wt0 + 16 * FDIM;
    uint4 b00 = *(const uint4*)(wt0 + 0);
    uint4 b01 = *(const uint4*)(wt0 + 32);
    uint4 b02 = *(const uint4*)(wt0 + 64);
    uint4 b03 = *(const uint4*)(wt0 + 96);
    uint4 b10 = *(const uint4*)(wt1 + 0);
    uint4 b11 = *(const uint4*)(wt1 + 32);
    uint4 b12 = *(const uint4*)(wt1 + 64);
    uint4 b13 = *(const uint4*)(wt1 + 96);
    const char* ab = (const char*)agg_h + lr * 256;
    const int sw = (lr & 7) << 4;
    uint4 a0 = *(const uint4*)(ab + ((0 * 64 + kq * 16) ^ sw));
    uint4 a1 = *(const uint4*)(ab + ((1 * 64 + kq * 16) ^ sw));
    uint4 a2 = *(const uint4*)(ab + ((2 * 64 + kq * 16) ^ sw));
    uint4 a3 = *(const uint4*)(ab + ((3 * 64 + kq * 16) ^ sw));
    f32x4 cA = {0, 0, 0, 0}, cB = {0, 0, 0, 0};
#define H8(x) __builtin_bit_cast(half8, x)
    cA = __builtin_amdgcn_mfma_f32_16x16x32_f16(H8(a0), H8(b00), cA, 0, 0, 0);
    cB = __builtin_amdgcn_mfma_f32_16x16x32_f16(H8(a0), H8(b10), cB, 0, 0, 0);
    cA = __builtin_amdgcn_mfma_f32_16x16x32_f16(H8(a1), H8(b01), cA, 0, 0, 0);
    cB = __builtin_amdgcn_mfma_f32_16x16x32_f16(H8(a1), H8(b11), cB, 0, 0, 0);
    cA = __builtin_amdgcn_mfma_f32_16x16x32_f16(H8(a2), H8(b02), cA, 0, 0, 0);
    cB = __builtin_amdgcn_mfma_f32_16x16x32_f16(H8(a2), H8(b12), cB, 0, 0, 0);
    cA = __builtin_amdgcn_mfma_f32_16x16x32_f16(H8(a3), H8(b03), cA, 0, 0, 0);
    cB = __builtin_amdgcn_mfma_f32_16x16x32_f16(H8(a3), H8(b13), cB, 0, 0, 0);
#undef H8
    // C layout: col = lane&15 (+tile), row = (lane>>4)*4 + reg
    const int orow = row_base + kq * 4;
    const int colA = w * 32 + lr, colB = colA + 16;
#pragma unroll
    for (int m = 0; m < 4; ++m) {
      h1[(size_t)(orow + m) * E1D + colA] = tanhf(cA[m]);
      h1[(size_t)(orow + m) * E1D + colB] = tanhf(cB[m]);
    }
  }
}

// h0: 4 seeds per block; neighbors+self f32; W0 fp16
__global__ __launch_bounds__(256) void h0_kernel(const int* __restrict__ nodes,
                                                 const int* __restrict__ nb1,
                                                 const float* __restrict__ degrees,
                                                 const float* __restrict__ features,
                                                 const __half* __restrict__ W0h,
                                                 float* __restrict__ h0) {
  const int t = threadIdx.x;
  const int s_base = blockIdx.x * 4;
  __shared__ float agg[4][FDIM];
  __shared__ int   nn_lds[4][NEI1];
  __shared__ float id_lds[4][NEI1];
  if (t < 4 * NEI1) {
    int r = t / NEI1, j = t - r * NEI1;
    int nn = nb1[(s_base + r) * NEI1 + j];
    nn_lds[r][j] = nn;
    id_lds[r][j] = 1.0f / degrees[nn];
  }
  __syncthreads();
  {
    int f = t & 127, rr = t >> 7;
#pragma unroll
    for (int h = 0; h < 2; ++h) {
      int r = rr + 2 * h;
      float acc = 0.0f;
#pragma unroll
      for (int j = 0; j < NEI1; ++j)
        acc += features[(size_t)nn_lds[r][j] * FDIM + f] * id_lds[r][j];
      agg[r][f] = features[(size_t)nodes[s_base + r] * FDIM + f] + acc * (1.0f / NEI1);
    }
  }
  __syncthreads();
  const int p = t & 63, q = t >> 6;    // row q, cols {2p, 2p+1}
  float d0 = 0.f, d1 = 0.f;
#pragma unroll 4
  for (int k4 = 0; k4 < FDIM; k4 += 4) {
    float4 a = *(const float4*)&agg[q][k4];
    float av[4] = {a.x, a.y, a.z, a.w};
#pragma unroll
    for (int kk = 0; kk < 4; ++kk) {
      float2 wv = __half22float2(*(const __half2*)(W0h + (size_t)(k4 + kk) * E1D + 2 * p));
      d0 += av[kk] * wv.x; d1 += av[kk] * wv.y;
    }
  }
  ((float2*)(h0 + (size_t)(s_base + q) * E1D))[p] = make_float2(tanhf(d0), tanhf(d1));
}

// layer1: 4 seeds per block; z = agg@Wm + eps*exp(agg@Ws)
__global__ __launch_bounds__(256) void layer1_kernel(const int* __restrict__ nb1,
                                                     const float* __restrict__ degrees,
                                                     const float* __restrict__ h0,
                                                     const float* __restrict__ h1,
                                                     const float* __restrict__ Wm,
                                                     const float* __restrict__ Ws,
                                                     float* __restrict__ z,
                                                     uint32_t k3a, uint32_t k3b) {
  const int t = threadIdx.x;
  const int s_base = blockIdx.x * 4;
  __shared__ float agg[4][E1D];
  __shared__ float id_lds[4][NEI1];
  if (t < 4 * NEI1) {
    int r = t / NEI1, j = t - r * NEI1;
    id_lds[r][j] = 1.0f / degrees[nb1[(s_base + r) * NEI1 + j]];
  }
  __syncthreads();
  {
    int f = t & 127, rr = t >> 7;
#pragma unroll
    for (int h = 0; h < 2; ++h) {
      int r = rr + 2 * h;
      float acc = 0.0f;
#pragma unroll
      for (int j = 0; j < NEI1; ++j)
        acc += h1[(size_t)((s_base + r) * NEI1 + j) * E1D + f] * id_lds[r][j];
      agg[r][f] = h0[(size_t)(s_base + r) * E1D + f] + acc * (1.0f / NEI1);
    }
  }
  __syncthreads();
  const int c = t & 63, q = t >> 6;    // row q, col c
  float zm = 0.f, zs = 0.f;
#pragma unroll 4
  for (int k4 = 0; k4 < E1D; k4 += 4) {
    float4 a = *(const float4*)&agg[q][k4];
    float av[4] = {a.x, a.y, a.z, a.w};
#pragma unroll
    for (int kk = 0; kk < 4; ++kk) {
      zm += av[kk] * Wm[(size_t)(k4 + kk) * E2D + c];
      zs += av[kk] * Ws[(size_t)(k4 + kk) * E2D + c];
    }
  }
  int b = s_base + q;
  uint32_t tt = (uint32_t)(b * E2D + c);
  uint32_t y0, y1;
  tf2x32(k3a, k3b, 0u, tt, &y0, &y1);
  uint32_t bits = y0 ^ y1;
  uint32_t fb = (bits >> 9) | 0x3F800000u;
  float fl = __uint_as_float(fb) - 1.0f;
  const float lo = -0.99999994f;
  float u = fmaxf(lo, fl * 2.0f + lo);
  float eps = 1.4142135381698608f * erfinv_xla(u);
  z[(size_t)b * E2D + c] = zm + eps * expf(zs);
}

// dec: 4 rows per block; logits = relu(z@W1+b1)@W2+b2; softmax
__global__ __launch_bounds__(256) void dec_kernel(const float* __restrict__ z,
                                                  const float* __restrict__ W1,
                                                  const float* __restrict__ b1,
                                                  const float* __restrict__ W2,
                                                  const float* __restrict__ b2,
                                                  float* __restrict__ out) {
  const int t = threadIdx.x;
  const int s_base = blockIdx.x * 4;
  __shared__ float zr[4][E2D];
  __shared__ float hid[4][DECD];
  __shared__ float lg[4][NCLS];
  zr[t >> 6][t & 63] = z[(size_t)s_base * E2D + t];
  __syncthreads();
  float h[4] = {0, 0, 0, 0};
#pragma unroll 4
  for (int k = 0; k < E2D; ++k) {
    float wv = W1[(size_t)k * DECD + t];
#pragma unroll
    for (int r = 0; r < 4; ++r) h[r] += zr[r][k] * wv;
  }
  float bb = b1[t];
#pragma unroll
  for (int r = 0; r < 4; ++r) hid[r][t] = fmaxf(h[r] + bb, 0.0f);
  __syncthreads();
  if (t < 4 * NCLS) {
    int r = t / NCLS, c = t - r * NCLS;
    float acc = 0.0f;
#pragma unroll 4
    for (int k = 0; k < DECD; ++k) acc += hid[r][k] * W2[(size_t)k * NCLS + c];
    lg[r][c] = acc + b2[c];
  }
  __syncthreads();
  const int l = t & 63, w = t >> 6;   // wave w -> row w
  float v = (l < NCLS) ? lg[w][l] : -3.0e38f;
  float m = v;
#pragma unroll
  for (int off = 32; off; off >>= 1) m = fmaxf(m, __shfl_xor(m, off));
  float e = (l < NCLS) ? expf(v - m) : 0.0f;
  float s = e;
#pragma unroll
  for (int off = 32; off; off >>= 1) s += __shfl_xor(s, off);
  if (l < NCLS) out[(size_t)(s_base + w) * NCLS + l] = e / s;
}

// ---------------- host helpers ----------------

// jax.random.permutation(key, 128), jax_threefry_partitionable:
// subkey = split(key)[1] = cipher(key, 0, 1);
// sort_keys[i] = (o0 ^ o1) of cipher(subkey, 0, i); stable sort of arange(128).
static void host_permutation(uint32_t ka, uint32_t kb, int count, int* out_idx) {
  uint32_t sa, sb;
  tf2x32(ka, kb, 0u, 1u, &sa, &sb);
  uint32_t keys[MAXDEG];
  int vals[MAXDEG];
  for (int i = 0; i < MAXDEG; ++i) {
    uint32_t y0, y1;
    tf2x32(sa, sb, 0u, (uint32_t)i, &y0, &y1);
    keys[i] = y0 ^ y1;
    vals[i] = i;
  }
  for (int i = 1; i < MAXDEG; ++i) {
    uint32_t kk = keys[i]; int vv = vals[i]; int j = i - 1;
    while (j >= 0 && keys[j] > kk) { keys[j+1] = keys[j]; vals[j+1] = vals[j]; --j; }
    keys[j+1] = kk; vals[j+1] = vv;
  }
  for (int i = 0; i < count; ++i) out_idx[i] = vals[i];
}

extern "C" void kernel_launch(void* const* d_in, const int* in_sizes, int n_in,
                              void* d_out, int out_size, void* d_ws, size_t ws_size,
                              hipStream_t stream) {
  const int*   nodes    = (const int*)  d_in[0];
  const int*   adj      = (const int*)  d_in[1];
  const float* degrees  = (const float*)d_in[2];
  const float* features = (const float*)d_in[3];
  const float* W0       = (const float*)d_in[4];
  const float* Wm       = (const float*)d_in[5];
  const float* Ws       = (const float*)d_in[6];
  const float* W1       = (const float*)d_in[7];
  const float* b1       = (const float*)d_in[8];
  const float* W2       = (const float*)d_in[9];
  const float* b2       = (const float*)d_in[10];
  float* out = (float*)d_out;

  uint32_t k1a, k1b, k2a, k2b, k3a, k3b;
  tf2x32(0u, 42u, 0u, 0u, &k1a, &k1b);
  tf2x32(0u, 42u, 0u, 1u, &k2a, &k2b);
  tf2x32(0u, 42u, 0u, 2u, &k3a, &k3b);

  PermArgs pa;
  host_permutation(k1a, k1b, NEI1, pa.p1);
  host_permutation(k2a, k2b, NEI0, pa.p2);

  // ---- workspace layout ----
  char* ws = (char*)d_ws;
  int*    nb1  = (int*)ws;                        // 163840 B
  float*  h1   = (float*)(ws + 163840);           // 20971520 B
  float*  h0   = (float*)(ws + 21135360);         // 2097152 B
  float*  z    = (float*)(ws + 23232512);         // 1048576 B
  __half* fh   = (__half*)(ws + 24281088);        // 25600000 B
  __half* W0h  = (__half*)(ws + 49881088);        // 32768 B
  __half* W0ht = (__half*)(ws + 49913856);        // 32768 B

  prep_kernel<<<CAST_FBLKS + CAST_WBLKS + WT_BLKS + NB1_BLKS, 256, 0, stream>>>(
      features, fh, W0, W0h, W0ht, nodes, adj, nb1, pa);
  h1_kernel<<<BATCH * NEI1 / H1_ROWS, 256, 0, stream>>>(
      nb1, adj, degrees, fh, W0ht, h1, pa);
  h0_kernel<<<BATCH / 4, 256, 0, stream>>>(nodes, nb1, degrees, features, W0h, h0);
  layer1_kernel<<<BATCH / 4, 256, 0, stream>>>(nb1, degrees, h0, h1, Wm, Ws, z, k3a, k3b);
  dec_kernel<<<BATCH / 4, 256, 0, stream>>>(z, W1, b1, W2, b2, out);
}